// Round 2
// baseline (1022.604 us; speedup 1.0000x reference)
//
#include <hip/hip_runtime.h>
#include <math.h>

// Problem constants (from reference)
#define NN 100000
#define EE 1600000
#define FIN 256
#define HID 64
#define CLS 40

// ---------------------------------------------------------------------------
// Degree: deg[n] = 1 (self loop) + #incoming edges on dst; dinv = rsqrt(deg)
// ---------------------------------------------------------------------------
__global__ __launch_bounds__(256) void k_deg_init(float* __restrict__ dinv) {
    int n = blockIdx.x * 256 + threadIdx.x;
    if (n < NN) dinv[n] = 1.0f;
}

__global__ __launch_bounds__(256) void k_deg_count(const int* __restrict__ dst,
                                                   float* __restrict__ dinv) {
    int e = blockIdx.x * 256 + threadIdx.x;
    if (e < EE) atomicAdd(&dinv[dst[e]], 1.0f);
}

__global__ __launch_bounds__(256) void k_deg_fin(float* __restrict__ dinv) {
    int n = blockIdx.x * 256 + threadIdx.x;
    if (n < NN) dinv[n] = rsqrtf(dinv[n]);
}

// ---------------------------------------------------------------------------
// GEMM1: h = x @ W1  [100000x256 @ 256x64], fp32 VALU.
// Epilogue stores:
//   hs   = h * dinv[r]              (pre-scaled source features for scatter)
//   acc1 = hs * dinv[r] + b1        (= h*dinv^2 + b1: self-loop term + bias)
// Block: 256 threads -> 256 rows x 64 cols; thread tile 8 rows x 8 cols.
// W1 (64KB) staged in LDS once. x read direct (each 64B line used over 4 k-steps).
// ---------------------------------------------------------------------------
__global__ __launch_bounds__(256) void k_gemm1(const float* __restrict__ x,
                                               const float* __restrict__ W1,
                                               const float* __restrict__ b1,
                                               const float* __restrict__ dinv,
                                               float* __restrict__ hs,
                                               float* __restrict__ acc1) {
    __shared__ float Wl[FIN * HID];  // 64 KB
    int tid = threadIdx.x;
    for (int i = tid; i < FIN * HID / 4; i += 256)
        ((float4*)Wl)[i] = ((const float4*)W1)[i];
    __syncthreads();

    int r0 = blockIdx.x * 256 + (tid >> 3) * 8;  // 8 rows per thread
    int c0 = (tid & 7) * 8;                      // 8 cols per thread

    float acc[8][8];
#pragma unroll
    for (int i = 0; i < 8; i++)
#pragma unroll
        for (int j = 0; j < 8; j++) acc[i][j] = 0.0f;

    for (int k = 0; k < FIN; k += 4) {
        float4 xv[8];
#pragma unroll
        for (int i = 0; i < 8; i++) {
            int r = r0 + i;
            xv[i] = (r < NN) ? *(const float4*)&x[(size_t)r * FIN + k]
                             : make_float4(0.f, 0.f, 0.f, 0.f);
        }
#pragma unroll
        for (int kk = 0; kk < 4; kk++) {
            float4 wa = *(const float4*)&Wl[(k + kk) * HID + c0];
            float4 wb = *(const float4*)&Wl[(k + kk) * HID + c0 + 4];
#pragma unroll
            for (int i = 0; i < 8; i++) {
                float xs = (kk == 0) ? xv[i].x : (kk == 1) ? xv[i].y
                         : (kk == 2) ? xv[i].z : xv[i].w;
                acc[i][0] += xs * wa.x;
                acc[i][1] += xs * wa.y;
                acc[i][2] += xs * wa.z;
                acc[i][3] += xs * wa.w;
                acc[i][4] += xs * wb.x;
                acc[i][5] += xs * wb.y;
                acc[i][6] += xs * wb.z;
                acc[i][7] += xs * wb.w;
            }
        }
    }

    float4 bA = *(const float4*)&b1[c0];
    float4 bB = *(const float4*)&b1[c0 + 4];
#pragma unroll
    for (int i = 0; i < 8; i++) {
        int r = r0 + i;
        if (r < NN) {
            float di = dinv[r];
            float4 sA = make_float4(acc[i][0] * di, acc[i][1] * di,
                                    acc[i][2] * di, acc[i][3] * di);
            float4 sB = make_float4(acc[i][4] * di, acc[i][5] * di,
                                    acc[i][6] * di, acc[i][7] * di);
            *(float4*)&hs[(size_t)r * HID + c0]     = sA;
            *(float4*)&hs[(size_t)r * HID + c0 + 4] = sB;
            float4 aA = make_float4(sA.x * di + bA.x, sA.y * di + bA.y,
                                    sA.z * di + bA.z, sA.w * di + bA.w);
            float4 aB = make_float4(sB.x * di + bB.x, sB.y * di + bB.y,
                                    sB.z * di + bB.z, sB.w * di + bB.w);
            *(float4*)&acc1[(size_t)r * HID + c0]     = aA;
            *(float4*)&acc1[(size_t)r * HID + c0 + 4] = aB;
        }
    }
}

// ---------------------------------------------------------------------------
// scatter1: acc1[d][c] += hs[s][c] * dinv[d].  One WAVE per edge:
// 64 lanes = 64 channels, edge index is wave-uniform (readfirstlane forces
// scalar s_load for src/dst/dinv), gather & atomic are 256B coalesced.
// ---------------------------------------------------------------------------
__global__ __launch_bounds__(256) void k_scatter1(const int* __restrict__ src,
                                                  const int* __restrict__ dst,
                                                  const float* __restrict__ dinv,
                                                  const float* __restrict__ hs,
                                                  float* __restrict__ acc1) {
    int lane = threadIdx.x & 63;
    unsigned wid = blockIdx.x * 4u + (threadIdx.x >> 6);  // wave id in grid
    unsigned nwaves = gridDim.x * 4u;
    for (unsigned e = wid; e < EE; e += nwaves) {
        int eu = __builtin_amdgcn_readfirstlane((int)e);
        int s = src[eu];
        int d = dst[eu];
        s = __builtin_amdgcn_readfirstlane(s);
        d = __builtin_amdgcn_readfirstlane(d);
        float dd = dinv[d];
        float v = hs[(size_t)s * HID + lane] * dd;
        atomicAdd(&acc1[(size_t)d * HID + lane], v);
    }
}

// ---------------------------------------------------------------------------
// GEMM2: h2 = relu(acc1) @ W2  [100000x64 @ 64x40]
// Epilogue stores:
//   h2s = h2 * dinv[r]
//   out = h2s * dinv[r] + b2   (self-loop + bias pre-seeded)
// Block: 256 threads -> 128 rows x 40 cols; thread tile 4 rows x 5 cols.
// ---------------------------------------------------------------------------
__global__ __launch_bounds__(256) void k_gemm2(const float* __restrict__ acc1,
                                               const float* __restrict__ W2,
                                               const float* __restrict__ b2,
                                               const float* __restrict__ dinv,
                                               float* __restrict__ h2s,
                                               float* __restrict__ out) {
    __shared__ float Wl[HID * CLS];  // 10 KB
    int tid = threadIdx.x;
    for (int i = tid; i < HID * CLS; i += 256) Wl[i] = W2[i];
    __syncthreads();

    int r0 = blockIdx.x * 128 + (tid >> 3) * 4;  // 4 rows per thread
    int c0 = (tid & 7) * 5;                      // 5 cols per thread

    float acc[4][5];
#pragma unroll
    for (int i = 0; i < 4; i++)
#pragma unroll
        for (int j = 0; j < 5; j++) acc[i][j] = 0.0f;

    for (int k = 0; k < HID; k += 4) {
        float4 xv[4];
#pragma unroll
        for (int i = 0; i < 4; i++) {
            int r = r0 + i;
            if (r < NN) {
                float4 v = *(const float4*)&acc1[(size_t)r * HID + k];
                v.x = fmaxf(v.x, 0.f);  // ReLU fused on load
                v.y = fmaxf(v.y, 0.f);
                v.z = fmaxf(v.z, 0.f);
                v.w = fmaxf(v.w, 0.f);
                xv[i] = v;
            } else {
                xv[i] = make_float4(0.f, 0.f, 0.f, 0.f);
            }
        }
#pragma unroll
        for (int kk = 0; kk < 4; kk++) {
            float wv[5];
#pragma unroll
            for (int j = 0; j < 5; j++) wv[j] = Wl[(k + kk) * CLS + c0 + j];
#pragma unroll
            for (int i = 0; i < 4; i++) {
                float xs = (kk == 0) ? xv[i].x : (kk == 1) ? xv[i].y
                         : (kk == 2) ? xv[i].z : xv[i].w;
#pragma unroll
                for (int j = 0; j < 5; j++) acc[i][j] += xs * wv[j];
            }
        }
    }

#pragma unroll
    for (int i = 0; i < 4; i++) {
        int r = r0 + i;
        if (r < NN) {
            float di = dinv[r];
#pragma unroll
            for (int j = 0; j < 5; j++) {
                float s = acc[i][j] * di;
                h2s[(size_t)r * CLS + c0 + j] = s;
                out[(size_t)r * CLS + c0 + j] = s * di + b2[c0 + j];
            }
        }
    }
}

// ---------------------------------------------------------------------------
// scatter2: out[d][c] += h2s[s][c] * dinv[d]; flat (edge,channel) grid.
// ---------------------------------------------------------------------------
__global__ __launch_bounds__(256) void k_scatter2(const int* __restrict__ src,
                                                  const int* __restrict__ dst,
                                                  const float* __restrict__ dinv,
                                                  const float* __restrict__ h2s,
                                                  float* __restrict__ out) {
    const unsigned total = (unsigned)EE * CLS;  // 64M < 2^31
    unsigned stride = gridDim.x * 256u;
    for (unsigned idx = blockIdx.x * 256u + threadIdx.x; idx < total; idx += stride) {
        unsigned e = idx / CLS;   // const division -> magic multiply
        unsigned c = idx - e * CLS;
        int s = src[e];
        int d = dst[e];
        float v = h2s[(size_t)s * CLS + c] * dinv[d];
        atomicAdd(&out[(size_t)d * CLS + c], v);
    }
}

// ---------------------------------------------------------------------------
// Launch
// ---------------------------------------------------------------------------
extern "C" void kernel_launch(void* const* d_in, const int* in_sizes, int n_in,
                              void* d_out, int out_size, void* d_ws, size_t ws_size,
                              hipStream_t stream) {
    const float* x   = (const float*)d_in[0];
    const float* W1  = (const float*)d_in[1];
    const float* b1  = (const float*)d_in[2];
    const float* W2  = (const float*)d_in[3];
    const float* b2  = (const float*)d_in[4];
    const int*   edg = (const int*)d_in[5];
    const int* src = edg;        // edges[0][:]
    const int* dst = edg + EE;   // edges[1][:]
    float* out = (float*)d_out;

    // Workspace layout (256B-aligned):
    //   dinv : NN floats       @ 0        (512 KB reserved)
    //   hs   : NN*HID floats   @ 512KB    (25.6 MB) -- reused as h2s by gemm2
    //   acc1 : NN*HID floats   @ 512KB + 25.6MB
    // Total ~51.8 MB.
    char* ws = (char*)d_ws;
    float* dinv = (float*)ws;
    float* hs   = (float*)(ws + (1 << 19));
    float* acc1 = (float*)(ws + (1 << 19) + (size_t)NN * HID * 4);
    float* h2s  = hs;  // hs buffer is dead after scatter1; reuse

    const int nb_n = (NN + 255) / 256;  // 391
    const int nb_e = (EE + 255) / 256;  // 6250

    k_deg_init<<<nb_n, 256, 0, stream>>>(dinv);
    k_deg_count<<<nb_e, 256, 0, stream>>>(dst, dinv);
    k_deg_fin<<<nb_n, 256, 0, stream>>>(dinv);

    k_gemm1<<<(NN + 255) / 256, 256, 0, stream>>>(x, W1, b1, dinv, hs, acc1);
    k_scatter1<<<8192, 256, 0, stream>>>(src, dst, dinv, hs, acc1);
    k_gemm2<<<(NN + 127) / 128, 256, 0, stream>>>(acc1, W2, b2, dinv, h2s, out);
    k_scatter2<<<8192, 256, 0, stream>>>(src, dst, dinv, h2s, out);
}

// Round 4
// 641.667 us; speedup vs baseline: 1.5937x; 1.5937x over previous
//
#include <hip/hip_runtime.h>
#include <math.h>

// Problem constants (from reference)
#define NN 100000
#define EE 1600000
#define FIN 256
#define HID 64
#define CLS 40
#define NB_N 391  // ceil(NN/256)

// ===========================================================================
// CSR build: deg -> exclusive scan -> cursor fill.  All int.
// ===========================================================================
__global__ __launch_bounds__(256) void k_zero(int* __restrict__ deg) {
    int n = blockIdx.x * 256 + threadIdx.x;
    if (n < NN) deg[n] = 0;
}

__global__ __launch_bounds__(256) void k_count(const int* __restrict__ dst,
                                               int* __restrict__ deg) {
    int e = blockIdx.x * 256 + threadIdx.x;
    if (e < EE) atomicAdd(&deg[dst[e]], 1);
}

// block sums of 256-wide tiles
__global__ __launch_bounds__(256) void k_scan_bsum(const int* __restrict__ deg,
                                                   int* __restrict__ bsum) {
    __shared__ int sm[256];
    int t = threadIdx.x;
    int n = blockIdx.x * 256 + t;
    sm[t] = (n < NN) ? deg[n] : 0;
    __syncthreads();
    for (int off = 128; off > 0; off >>= 1) {
        if (t < off) sm[t] += sm[t + off];
        __syncthreads();
    }
    if (t == 0) bsum[blockIdx.x] = sm[0];
}

// exclusive scan of NB_N block sums (single block, 512 threads)
__global__ __launch_bounds__(512) void k_scan_boff(const int* __restrict__ bsum,
                                                   int* __restrict__ boff) {
    __shared__ int sm[512];
    int t = threadIdx.x;
    int v = (t < NB_N) ? bsum[t] : 0;
    sm[t] = v;
    __syncthreads();
    for (int off = 1; off < 512; off <<= 1) {
        int u = (t >= off) ? sm[t - off] : 0;
        __syncthreads();
        sm[t] += u;
        __syncthreads();
    }
    if (t < NB_N) boff[t] = sm[t] - v;  // exclusive
}

// local exclusive scan + block offset -> row_ptr & fill cursor; also dinv
__global__ __launch_bounds__(256) void k_scan_fin(const int* __restrict__ deg,
                                                  const int* __restrict__ boff,
                                                  int* __restrict__ rowp,
                                                  int* __restrict__ cursor,
                                                  float* __restrict__ dinv) {
    __shared__ int sm[256];
    int t = threadIdx.x;
    int n = blockIdx.x * 256 + t;
    int v = (n < NN) ? deg[n] : 0;
    sm[t] = v;
    __syncthreads();
    for (int off = 1; off < 256; off <<= 1) {
        int u = (t >= off) ? sm[t - off] : 0;
        __syncthreads();
        sm[t] += u;
        __syncthreads();
    }
    if (n < NN) {
        int start = boff[blockIdx.x] + sm[t] - v;
        rowp[n] = start;
        cursor[n] = start;
        dinv[n] = rsqrtf((float)(v + 1));  // +1 self loop
    }
}

__global__ __launch_bounds__(256) void k_fill(const int* __restrict__ src,
                                              const int* __restrict__ dst,
                                              int* __restrict__ cursor,
                                              int* __restrict__ csr) {
    int e = blockIdx.x * 256 + threadIdx.x;
    if (e < EE) {
        int d = dst[e];
        int pos = atomicAdd(&cursor[d], 1);
        csr[pos] = src[e];
    }
}

// dinv only (fallback path, no CSR)
__global__ __launch_bounds__(256) void k_dinv(const int* __restrict__ deg,
                                              float* __restrict__ dinv) {
    int n = blockIdx.x * 256 + threadIdx.x;
    if (n < NN) dinv[n] = rsqrtf((float)(deg[n] + 1));
}

// ===========================================================================
// GEMM1: hs = (x @ W1) * dinv[r]   [100000x256 @ 256x64]
// Block: 256 threads -> 256 rows x 64 cols; thread tile 8x8. W1 in LDS.
// Lanes 0-7 of each row-group load identical x addresses (HW broadcast), so
// x HBM traffic is read-once (~100 MB).
// ===========================================================================
__global__ __launch_bounds__(256) void k_gemm1(const float* __restrict__ x,
                                               const float* __restrict__ W1,
                                               const float* __restrict__ dinv,
                                               float* __restrict__ hs) {
    __shared__ float Wl[FIN * HID];  // 64 KB
    int tid = threadIdx.x;
    for (int i = tid; i < FIN * HID / 4; i += 256)
        ((float4*)Wl)[i] = ((const float4*)W1)[i];
    __syncthreads();

    int r0 = blockIdx.x * 256 + (tid >> 3) * 8;
    int c0 = (tid & 7) * 8;

    float acc[8][8];
#pragma unroll
    for (int i = 0; i < 8; i++)
#pragma unroll
        for (int j = 0; j < 8; j++) acc[i][j] = 0.0f;

    for (int k = 0; k < FIN; k += 4) {
        float4 xv[8];
#pragma unroll
        for (int i = 0; i < 8; i++) {
            int r = r0 + i;
            xv[i] = (r < NN) ? *(const float4*)&x[(size_t)r * FIN + k]
                             : make_float4(0.f, 0.f, 0.f, 0.f);
        }
#pragma unroll
        for (int kk = 0; kk < 4; kk++) {
            float4 wa = *(const float4*)&Wl[(k + kk) * HID + c0];
            float4 wb = *(const float4*)&Wl[(k + kk) * HID + c0 + 4];
#pragma unroll
            for (int i = 0; i < 8; i++) {
                float xs = (kk == 0) ? xv[i].x : (kk == 1) ? xv[i].y
                         : (kk == 2) ? xv[i].z : xv[i].w;
                acc[i][0] += xs * wa.x;
                acc[i][1] += xs * wa.y;
                acc[i][2] += xs * wa.z;
                acc[i][3] += xs * wa.w;
                acc[i][4] += xs * wb.x;
                acc[i][5] += xs * wb.y;
                acc[i][6] += xs * wb.z;
                acc[i][7] += xs * wb.w;
            }
        }
    }

#pragma unroll
    for (int i = 0; i < 8; i++) {
        int r = r0 + i;
        if (r < NN) {
            float di = dinv[r];
            float4 sA = make_float4(acc[i][0] * di, acc[i][1] * di,
                                    acc[i][2] * di, acc[i][3] * di);
            float4 sB = make_float4(acc[i][4] * di, acc[i][5] * di,
                                    acc[i][6] * di, acc[i][7] * di);
            *(float4*)&hs[(size_t)r * HID + c0]     = sA;
            *(float4*)&hs[(size_t)r * HID + c0 + 4] = sB;
        }
    }
}

// ===========================================================================
// agg1: acc1[d][c] = (hs[d][c] + sum_{e in CSR[d]} hs[src_e][c]) * dinv[d] + b1[c]
// One WAVE per node, 64 lanes = 64 channels. No atomics. Unroll-4 for MLP
// (4 gathers in flight). csr loads are wave-uniform -> broadcast.
// ===========================================================================
__global__ __launch_bounds__(256) void k_agg1(const int* __restrict__ rowp,
                                              const int* __restrict__ deg,
                                              const int* __restrict__ csr,
                                              const float* __restrict__ dinv,
                                              const float* __restrict__ b1,
                                              const float* __restrict__ hs,
                                              float* __restrict__ acc1) {
    int lane = threadIdx.x & 63;
    int n = blockIdx.x * 4 + (threadIdx.x >> 6);
    if (n >= NN) return;
    int rp  = __builtin_amdgcn_readfirstlane(rowp[n]);
    int cnt = __builtin_amdgcn_readfirstlane(deg[n]);

    float acc = hs[(size_t)n * HID + lane];  // self loop
    int e = 0;
    for (; e + 4 <= cnt; e += 4) {
        int s0 = __builtin_amdgcn_readfirstlane(csr[rp + e]);
        int s1 = __builtin_amdgcn_readfirstlane(csr[rp + e + 1]);
        int s2 = __builtin_amdgcn_readfirstlane(csr[rp + e + 2]);
        int s3 = __builtin_amdgcn_readfirstlane(csr[rp + e + 3]);
        float v0 = hs[(size_t)s0 * HID + lane];
        float v1 = hs[(size_t)s1 * HID + lane];
        float v2 = hs[(size_t)s2 * HID + lane];
        float v3 = hs[(size_t)s3 * HID + lane];
        acc += (v0 + v1) + (v2 + v3);
    }
    for (; e < cnt; e++) {
        int s = __builtin_amdgcn_readfirstlane(csr[rp + e]);
        acc += hs[(size_t)s * HID + lane];
    }
    acc1[(size_t)n * HID + lane] = acc * dinv[n] + b1[lane];
}

// ===========================================================================
// GEMM2: h2s = (relu(acc1) @ W2) * dinv[r]   [100000x64 @ 64x40]
// Block: 256 threads -> 128 rows x 40 cols; thread tile 4x5. W2 in LDS.
// ===========================================================================
__global__ __launch_bounds__(256) void k_gemm2(const float* __restrict__ acc1,
                                               const float* __restrict__ W2,
                                               const float* __restrict__ dinv,
                                               float* __restrict__ h2s) {
    __shared__ float Wl[HID * CLS];  // 10 KB
    int tid = threadIdx.x;
    for (int i = tid; i < HID * CLS; i += 256) Wl[i] = W2[i];
    __syncthreads();

    int r0 = blockIdx.x * 128 + (tid >> 3) * 4;
    int c0 = (tid & 7) * 5;

    float acc[4][5];
#pragma unroll
    for (int i = 0; i < 4; i++)
#pragma unroll
        for (int j = 0; j < 5; j++) acc[i][j] = 0.0f;

    for (int k = 0; k < HID; k += 4) {
        float4 xv[4];
#pragma unroll
        for (int i = 0; i < 4; i++) {
            int r = r0 + i;
            if (r < NN) {
                float4 v = *(const float4*)&acc1[(size_t)r * HID + k];
                v.x = fmaxf(v.x, 0.f);
                v.y = fmaxf(v.y, 0.f);
                v.z = fmaxf(v.z, 0.f);
                v.w = fmaxf(v.w, 0.f);
                xv[i] = v;
            } else {
                xv[i] = make_float4(0.f, 0.f, 0.f, 0.f);
            }
        }
#pragma unroll
        for (int kk = 0; kk < 4; kk++) {
            float wv[5];
#pragma unroll
            for (int j = 0; j < 5; j++) wv[j] = Wl[(k + kk) * CLS + c0 + j];
#pragma unroll
            for (int i = 0; i < 4; i++) {
                float xs = (kk == 0) ? xv[i].x : (kk == 1) ? xv[i].y
                         : (kk == 2) ? xv[i].z : xv[i].w;
#pragma unroll
                for (int j = 0; j < 5; j++) acc[i][j] += xs * wv[j];
            }
        }
    }

#pragma unroll
    for (int i = 0; i < 4; i++) {
        int r = r0 + i;
        if (r < NN) {
            float di = dinv[r];
#pragma unroll
            for (int j = 0; j < 5; j++)
                h2s[(size_t)r * CLS + c0 + j] = acc[i][j] * di;
        }
    }
}

// ===========================================================================
// agg2: out[d][c] = (h2s[d][c] + sum_e h2s[src_e][c]) * dinv[d] + b2[c]
// One WAVE per node; lanes >= CLS read duplicate addr (free broadcast), masked
// on store. No atomics.
// ===========================================================================
__global__ __launch_bounds__(256) void k_agg2(const int* __restrict__ rowp,
                                              const int* __restrict__ deg,
                                              const int* __restrict__ csr,
                                              const float* __restrict__ dinv,
                                              const float* __restrict__ b2,
                                              const float* __restrict__ h2s,
                                              float* __restrict__ out) {
    int lane = threadIdx.x & 63;
    int cl = lane < CLS ? lane : CLS - 1;  // avoid divergent loop body
    int n = blockIdx.x * 4 + (threadIdx.x >> 6);
    if (n >= NN) return;
    int rp  = __builtin_amdgcn_readfirstlane(rowp[n]);
    int cnt = __builtin_amdgcn_readfirstlane(deg[n]);

    float acc = h2s[(size_t)n * CLS + cl];  // self loop
    int e = 0;
    for (; e + 4 <= cnt; e += 4) {
        int s0 = __builtin_amdgcn_readfirstlane(csr[rp + e]);
        int s1 = __builtin_amdgcn_readfirstlane(csr[rp + e + 1]);
        int s2 = __builtin_amdgcn_readfirstlane(csr[rp + e + 2]);
        int s3 = __builtin_amdgcn_readfirstlane(csr[rp + e + 3]);
        float v0 = h2s[(size_t)s0 * CLS + cl];
        float v1 = h2s[(size_t)s1 * CLS + cl];
        float v2 = h2s[(size_t)s2 * CLS + cl];
        float v3 = h2s[(size_t)s3 * CLS + cl];
        acc += (v0 + v1) + (v2 + v3);
    }
    for (; e < cnt; e++) {
        int s = __builtin_amdgcn_readfirstlane(csr[rp + e]);
        acc += h2s[(size_t)s * CLS + cl];
    }
    if (lane < CLS)
        out[(size_t)n * CLS + lane] = acc * dinv[n] + b2[lane];
}

// ===========================================================================
// Fallback path (small workspace): seed + atomic scatter (round-2 design)
// ===========================================================================
__global__ __launch_bounds__(256) void k_seed1(const float* __restrict__ hs,
                                               const float* __restrict__ dinv,
                                               const float* __restrict__ b1,
                                               float* __restrict__ acc1) {
    int idx = blockIdx.x * 256 + threadIdx.x;  // over NN*HID
    if (idx < NN * HID) {
        int r = idx >> 6, c = idx & 63;
        acc1[idx] = hs[idx] * dinv[r] + b1[c];
    }
}

__global__ __launch_bounds__(256) void k_scatter1(const int* __restrict__ src,
                                                  const int* __restrict__ dst,
                                                  const float* __restrict__ dinv,
                                                  const float* __restrict__ hs,
                                                  float* __restrict__ acc1) {
    int lane = threadIdx.x & 63;
    unsigned wid = blockIdx.x * 4u + (threadIdx.x >> 6);
    unsigned nwaves = gridDim.x * 4u;
    for (unsigned e = wid; e < EE; e += nwaves) {
        int eu = __builtin_amdgcn_readfirstlane((int)e);
        int s = __builtin_amdgcn_readfirstlane(src[eu]);
        int d = __builtin_amdgcn_readfirstlane(dst[eu]);
        float v = hs[(size_t)s * HID + lane] * dinv[d];
        atomicAdd(&acc1[(size_t)d * HID + lane], v);
    }
}

__global__ __launch_bounds__(256) void k_seed2(const float* __restrict__ h2s,
                                               const float* __restrict__ dinv,
                                               const float* __restrict__ b2,
                                               float* __restrict__ out) {
    int idx = blockIdx.x * 256 + threadIdx.x;  // over NN*CLS
    if (idx < NN * CLS) {
        int r = idx / CLS, c = idx - r * CLS;
        out[idx] = h2s[idx] * dinv[r] + b2[c];
    }
}

__global__ __launch_bounds__(256) void k_scatter2(const int* __restrict__ src,
                                                  const int* __restrict__ dst,
                                                  const float* __restrict__ dinv,
                                                  const float* __restrict__ h2s,
                                                  float* __restrict__ out) {
    const unsigned total = (unsigned)EE * CLS;
    unsigned stride = gridDim.x * 256u;
    for (unsigned idx = blockIdx.x * 256u + threadIdx.x; idx < total; idx += stride) {
        unsigned e = idx / CLS;
        unsigned c = idx - e * CLS;
        int s = src[e];
        int d = dst[e];
        float v = h2s[(size_t)s * CLS + c] * dinv[d];
        atomicAdd(&out[(size_t)d * CLS + c], v);
    }
}

// ===========================================================================
// Launch
// ===========================================================================
extern "C" void kernel_launch(void* const* d_in, const int* in_sizes, int n_in,
                              void* d_out, int out_size, void* d_ws, size_t ws_size,
                              hipStream_t stream) {
    const float* x   = (const float*)d_in[0];
    const float* W1  = (const float*)d_in[1];
    const float* b1  = (const float*)d_in[2];
    const float* W2  = (const float*)d_in[3];
    const float* b2  = (const float*)d_in[4];
    const int*   edg = (const int*)d_in[5];
    const int* src = edg;        // edges[0][:]
    const int* dst = edg + EE;   // edges[1][:]
    float* out = (float*)d_out;
    char* ws = (char*)d_ws;

    const int nb_n = NB_N;               // 391
    const int nb_e = (EE + 255) / 256;   // 6250

    // CSR-path workspace layout:
    //   deg   @ 0         (512 KB)   rowp @ 512K   dinv @ 1M   bsum @ 1.5M
    //   boff  @ 1.75M     csr  @ 2M  (6.4 MB)
    //   hs    @ 10M       (25.6 MB; reused as h2s [16 MB] after agg1)
    //   acc1  @ 36M       (25.6 MB; first 400 KB doubles as cursor pre-agg1)
    const size_t NEED = (size_t)(36 << 20) + (size_t)NN * HID * 4;  // ~60.4 MB

    if (ws_size >= NEED) {
        int*   deg    = (int*)(ws);
        int*   rowp   = (int*)(ws + (512 << 10));
        float* dinv   = (float*)(ws + (1 << 20));
        int*   bsum   = (int*)(ws + ((1 << 20) + (512 << 10)));
        int*   boff   = (int*)(ws + ((1 << 20) + (768 << 10)));
        int*   csr    = (int*)(ws + (2 << 20));
        float* hs     = (float*)(ws + (10 << 20));
        float* acc1   = (float*)(ws + (36 << 20));
        int*   cursor = (int*)acc1;     // dead before agg1 writes acc1
        float* h2s    = hs;             // hs dead after agg1

        k_zero<<<nb_n, 256, 0, stream>>>(deg);
        k_count<<<nb_e, 256, 0, stream>>>(dst, deg);
        k_scan_bsum<<<nb_n, 256, 0, stream>>>(deg, bsum);
        k_scan_boff<<<1, 512, 0, stream>>>(bsum, boff);
        k_scan_fin<<<nb_n, 256, 0, stream>>>(deg, boff, rowp, cursor, dinv);
        k_fill<<<nb_e, 256, 0, stream>>>(src, dst, cursor, csr);

        k_gemm1<<<(NN + 255) / 256, 256, 0, stream>>>(x, W1, dinv, hs);
        k_agg1<<<(NN + 3) / 4, 256, 0, stream>>>(rowp, deg, csr, dinv, b1, hs, acc1);
        k_gemm2<<<(NN + 127) / 128, 256, 0, stream>>>(acc1, W2, dinv, h2s);
        k_agg2<<<(NN + 3) / 4, 256, 0, stream>>>(rowp, deg, csr, dinv, b2, h2s, out);
    } else {
        // Fallback: atomic scatter (round-2 design), ~53 MB
        int*   deg  = (int*)(ws);
        float* dinv = (float*)(ws + (512 << 10));
        float* hs   = (float*)(ws + (1 << 20));
        float* acc1 = (float*)(ws + (1 << 20) + (size_t)NN * HID * 4);
        float* h2s  = hs;

        k_zero<<<nb_n, 256, 0, stream>>>(deg);
        k_count<<<nb_e, 256, 0, stream>>>(dst, deg);
        k_dinv<<<nb_n, 256, 0, stream>>>(deg, dinv);

        k_gemm1<<<(NN + 255) / 256, 256, 0, stream>>>(x, W1, dinv, hs);
        k_seed1<<<(NN * HID + 255) / 256, 256, 0, stream>>>(hs, dinv, b1, acc1);
        k_scatter1<<<8192, 256, 0, stream>>>(src, dst, dinv, hs, acc1);
        k_gemm2<<<(NN + 127) / 128, 256, 0, stream>>>(acc1, W2, dinv, h2s);
        k_seed2<<<(NN * CLS + 255) / 256, 256, 0, stream>>>(h2s, dinv, b2, out);
        k_scatter2<<<8192, 256, 0, stream>>>(src, dst, dinv, h2s, out);
    }
}

// Round 5
// 609.652 us; speedup vs baseline: 1.6774x; 1.0525x over previous
//
#include <hip/hip_runtime.h>
#include <math.h>

// Problem constants (from reference)
#define NN 100000
#define EE 1600000
#define FIN 256
#define HID 64
#define CLS 40
#define NB_N 391  // ceil(NN/256)

// ===========================================================================
// CSR build: deg -> exclusive scan -> cursor fill.  All int.
// ===========================================================================
__global__ __launch_bounds__(256) void k_zero(int* __restrict__ deg) {
    int n = blockIdx.x * 256 + threadIdx.x;
    if (n < NN) deg[n] = 0;
}

__global__ __launch_bounds__(256) void k_count(const int* __restrict__ dst,
                                               int* __restrict__ deg) {
    int e = blockIdx.x * 256 + threadIdx.x;
    if (e < EE) atomicAdd(&deg[dst[e]], 1);
}

// block sums of 256-wide tiles
__global__ __launch_bounds__(256) void k_scan_bsum(const int* __restrict__ deg,
                                                   int* __restrict__ bsum) {
    __shared__ int sm[256];
    int t = threadIdx.x;
    int n = blockIdx.x * 256 + t;
    sm[t] = (n < NN) ? deg[n] : 0;
    __syncthreads();
    for (int off = 128; off > 0; off >>= 1) {
        if (t < off) sm[t] += sm[t + off];
        __syncthreads();
    }
    if (t == 0) bsum[blockIdx.x] = sm[0];
}

// exclusive scan of NB_N block sums (single block, 512 threads)
__global__ __launch_bounds__(512) void k_scan_boff(const int* __restrict__ bsum,
                                                   int* __restrict__ boff) {
    __shared__ int sm[512];
    int t = threadIdx.x;
    int v = (t < NB_N) ? bsum[t] : 0;
    sm[t] = v;
    __syncthreads();
    for (int off = 1; off < 512; off <<= 1) {
        int u = (t >= off) ? sm[t - off] : 0;
        __syncthreads();
        sm[t] += u;
        __syncthreads();
    }
    if (t < NB_N) boff[t] = sm[t] - v;  // exclusive
}

// local exclusive scan + block offset -> row_ptr & fill cursor; also dinv
__global__ __launch_bounds__(256) void k_scan_fin(const int* __restrict__ deg,
                                                  const int* __restrict__ boff,
                                                  int* __restrict__ rowp,
                                                  int* __restrict__ cursor,
                                                  float* __restrict__ dinv) {
    __shared__ int sm[256];
    int t = threadIdx.x;
    int n = blockIdx.x * 256 + t;
    int v = (n < NN) ? deg[n] : 0;
    sm[t] = v;
    __syncthreads();
    for (int off = 1; off < 256; off <<= 1) {
        int u = (t >= off) ? sm[t - off] : 0;
        __syncthreads();
        sm[t] += u;
        __syncthreads();
    }
    if (n < NN) {
        int start = boff[blockIdx.x] + sm[t] - v;
        rowp[n] = start;
        cursor[n] = start;
        dinv[n] = rsqrtf((float)(v + 1));  // +1 self loop
    }
}

__global__ __launch_bounds__(256) void k_fill(const int* __restrict__ src,
                                              const int* __restrict__ dst,
                                              int* __restrict__ cursor,
                                              int* __restrict__ csr) {
    int e = blockIdx.x * 256 + threadIdx.x;
    if (e < EE) {
        int d = dst[e];
        int pos = atomicAdd(&cursor[d], 1);
        csr[pos] = src[e];
    }
}

// dinv only (fallback path, no CSR)
__global__ __launch_bounds__(256) void k_dinv(const int* __restrict__ deg,
                                              float* __restrict__ dinv) {
    int n = blockIdx.x * 256 + threadIdx.x;
    if (n < NN) dinv[n] = rsqrtf((float)(deg[n] + 1));
}

// ===========================================================================
// GEMM1: hs = (x @ W1) * dinv[r]   [100000x256 @ 256x64]
// v2: occupancy-first. 64 rows x 64 cols per 256-thread block (grid 1563 =
// ~6 blocks/CU; was 391 = 1.5/CU at 13.6% occupancy). NO LDS (was 64 KB,
// capping 2 blocks/CU): W1 is 64 KB and L1/L2-resident, read direct.
// Thread tile 4 rows x 4 cols; c0=(tid&15)*4 so each W row-slice load is
// 16 lanes x contiguous float4 = one coalesced 256B access, broadcast
// across the 4 row-groups.
// ===========================================================================
__global__ __launch_bounds__(256) void k_gemm1(const float* __restrict__ x,
                                               const float* __restrict__ W1,
                                               const float* __restrict__ dinv,
                                               float* __restrict__ hs) {
    int tid = threadIdx.x;
    int r0 = blockIdx.x * 64 + (tid >> 4) * 4;  // 16 row-groups x 4 rows
    int c0 = (tid & 15) * 4;                    // 16 col-groups x 4 cols

    float acc[4][4];
#pragma unroll
    for (int i = 0; i < 4; i++)
#pragma unroll
        for (int j = 0; j < 4; j++) acc[i][j] = 0.0f;

    for (int k = 0; k < FIN; k += 4) {
        float4 xv[4];
#pragma unroll
        for (int i = 0; i < 4; i++) {
            int r = r0 + i;
            xv[i] = (r < NN) ? *(const float4*)&x[(size_t)r * FIN + k]
                             : make_float4(0.f, 0.f, 0.f, 0.f);
        }
#pragma unroll
        for (int kk = 0; kk < 4; kk++) {
            float4 wv = *(const float4*)&W1[(k + kk) * HID + c0];
#pragma unroll
            for (int i = 0; i < 4; i++) {
                float xs = (kk == 0) ? xv[i].x : (kk == 1) ? xv[i].y
                         : (kk == 2) ? xv[i].z : xv[i].w;
                acc[i][0] += xs * wv.x;
                acc[i][1] += xs * wv.y;
                acc[i][2] += xs * wv.z;
                acc[i][3] += xs * wv.w;
            }
        }
    }

#pragma unroll
    for (int i = 0; i < 4; i++) {
        int r = r0 + i;
        if (r < NN) {
            float di = dinv[r];
            float4 sv = make_float4(acc[i][0] * di, acc[i][1] * di,
                                    acc[i][2] * di, acc[i][3] * di);
            *(float4*)&hs[(size_t)r * HID + c0] = sv;
        }
    }
}

// ===========================================================================
// agg1: acc1[d][c] = (hs[d][c] + sum_{e in CSR[d]} hs[src_e][c]) * dinv[d] + b1[c]
// One WAVE per node, 64 lanes = 64 channels. No atomics. Unroll-4 for MLP
// (4 gathers in flight). csr loads are wave-uniform -> broadcast.
// ===========================================================================
__global__ __launch_bounds__(256) void k_agg1(const int* __restrict__ rowp,
                                              const int* __restrict__ deg,
                                              const int* __restrict__ csr,
                                              const float* __restrict__ dinv,
                                              const float* __restrict__ b1,
                                              const float* __restrict__ hs,
                                              float* __restrict__ acc1) {
    int lane = threadIdx.x & 63;
    int n = blockIdx.x * 4 + (threadIdx.x >> 6);
    if (n >= NN) return;
    int rp  = __builtin_amdgcn_readfirstlane(rowp[n]);
    int cnt = __builtin_amdgcn_readfirstlane(deg[n]);

    float acc = hs[(size_t)n * HID + lane];  // self loop
    int e = 0;
    for (; e + 4 <= cnt; e += 4) {
        int s0 = __builtin_amdgcn_readfirstlane(csr[rp + e]);
        int s1 = __builtin_amdgcn_readfirstlane(csr[rp + e + 1]);
        int s2 = __builtin_amdgcn_readfirstlane(csr[rp + e + 2]);
        int s3 = __builtin_amdgcn_readfirstlane(csr[rp + e + 3]);
        float v0 = hs[(size_t)s0 * HID + lane];
        float v1 = hs[(size_t)s1 * HID + lane];
        float v2 = hs[(size_t)s2 * HID + lane];
        float v3 = hs[(size_t)s3 * HID + lane];
        acc += (v0 + v1) + (v2 + v3);
    }
    for (; e < cnt; e++) {
        int s = __builtin_amdgcn_readfirstlane(csr[rp + e]);
        acc += hs[(size_t)s * HID + lane];
    }
    acc1[(size_t)n * HID + lane] = acc * dinv[n] + b1[lane];
}

// ===========================================================================
// GEMM2: h2s = (relu(acc1) @ W2) * dinv[r]   [100000x64 @ 64x40]
// Block: 256 threads -> 128 rows x 40 cols; thread tile 4x5. W2 in LDS (10KB).
// ===========================================================================
__global__ __launch_bounds__(256) void k_gemm2(const float* __restrict__ acc1,
                                               const float* __restrict__ W2,
                                               const float* __restrict__ dinv,
                                               float* __restrict__ h2s) {
    __shared__ float Wl[HID * CLS];  // 10 KB
    int tid = threadIdx.x;
    for (int i = tid; i < HID * CLS; i += 256) Wl[i] = W2[i];
    __syncthreads();

    int r0 = blockIdx.x * 128 + (tid >> 3) * 4;
    int c0 = (tid & 7) * 5;

    float acc[4][5];
#pragma unroll
    for (int i = 0; i < 4; i++)
#pragma unroll
        for (int j = 0; j < 5; j++) acc[i][j] = 0.0f;

    for (int k = 0; k < HID; k += 4) {
        float4 xv[4];
#pragma unroll
        for (int i = 0; i < 4; i++) {
            int r = r0 + i;
            if (r < NN) {
                float4 v = *(const float4*)&acc1[(size_t)r * HID + k];
                v.x = fmaxf(v.x, 0.f);
                v.y = fmaxf(v.y, 0.f);
                v.z = fmaxf(v.z, 0.f);
                v.w = fmaxf(v.w, 0.f);
                xv[i] = v;
            } else {
                xv[i] = make_float4(0.f, 0.f, 0.f, 0.f);
            }
        }
#pragma unroll
        for (int kk = 0; kk < 4; kk++) {
            float wv[5];
#pragma unroll
            for (int j = 0; j < 5; j++) wv[j] = Wl[(k + kk) * CLS + c0 + j];
#pragma unroll
            for (int i = 0; i < 4; i++) {
                float xs = (kk == 0) ? xv[i].x : (kk == 1) ? xv[i].y
                         : (kk == 2) ? xv[i].z : xv[i].w;
#pragma unroll
                for (int j = 0; j < 5; j++) acc[i][j] += xs * wv[j];
            }
        }
    }

#pragma unroll
    for (int i = 0; i < 4; i++) {
        int r = r0 + i;
        if (r < NN) {
            float di = dinv[r];
#pragma unroll
            for (int j = 0; j < 5; j++)
                h2s[(size_t)r * CLS + c0 + j] = acc[i][j] * di;
        }
    }
}

// ===========================================================================
// agg2: out[d][c] = (h2s[d][c] + sum_e h2s[src_e][c]) * dinv[d] + b2[c]
// One WAVE per node; lanes >= CLS read duplicate addr (free broadcast), masked
// on store. No atomics.
// ===========================================================================
__global__ __launch_bounds__(256) void k_agg2(const int* __restrict__ rowp,
                                              const int* __restrict__ deg,
                                              const int* __restrict__ csr,
                                              const float* __restrict__ dinv,
                                              const float* __restrict__ b2,
                                              const float* __restrict__ h2s,
                                              float* __restrict__ out) {
    int lane = threadIdx.x & 63;
    int cl = lane < CLS ? lane : CLS - 1;  // avoid divergent loop body
    int n = blockIdx.x * 4 + (threadIdx.x >> 6);
    if (n >= NN) return;
    int rp  = __builtin_amdgcn_readfirstlane(rowp[n]);
    int cnt = __builtin_amdgcn_readfirstlane(deg[n]);

    float acc = h2s[(size_t)n * CLS + cl];  // self loop
    int e = 0;
    for (; e + 4 <= cnt; e += 4) {
        int s0 = __builtin_amdgcn_readfirstlane(csr[rp + e]);
        int s1 = __builtin_amdgcn_readfirstlane(csr[rp + e + 1]);
        int s2 = __builtin_amdgcn_readfirstlane(csr[rp + e + 2]);
        int s3 = __builtin_amdgcn_readfirstlane(csr[rp + e + 3]);
        float v0 = h2s[(size_t)s0 * CLS + cl];
        float v1 = h2s[(size_t)s1 * CLS + cl];
        float v2 = h2s[(size_t)s2 * CLS + cl];
        float v3 = h2s[(size_t)s3 * CLS + cl];
        acc += (v0 + v1) + (v2 + v3);
    }
    for (; e < cnt; e++) {
        int s = __builtin_amdgcn_readfirstlane(csr[rp + e]);
        acc += h2s[(size_t)s * CLS + cl];
    }
    if (lane < CLS)
        out[(size_t)n * CLS + lane] = acc * dinv[n] + b2[lane];
}

// ===========================================================================
// Fallback path (small workspace): seed + atomic scatter (round-2 design)
// ===========================================================================
__global__ __launch_bounds__(256) void k_seed1(const float* __restrict__ hs,
                                               const float* __restrict__ dinv,
                                               const float* __restrict__ b1,
                                               float* __restrict__ acc1) {
    int idx = blockIdx.x * 256 + threadIdx.x;  // over NN*HID
    if (idx < NN * HID) {
        int r = idx >> 6, c = idx & 63;
        acc1[idx] = hs[idx] * dinv[r] + b1[c];
    }
}

__global__ __launch_bounds__(256) void k_scatter1(const int* __restrict__ src,
                                                  const int* __restrict__ dst,
                                                  const float* __restrict__ dinv,
                                                  const float* __restrict__ hs,
                                                  float* __restrict__ acc1) {
    int lane = threadIdx.x & 63;
    unsigned wid = blockIdx.x * 4u + (threadIdx.x >> 6);
    unsigned nwaves = gridDim.x * 4u;
    for (unsigned e = wid; e < EE; e += nwaves) {
        int eu = __builtin_amdgcn_readfirstlane((int)e);
        int s = __builtin_amdgcn_readfirstlane(src[eu]);
        int d = __builtin_amdgcn_readfirstlane(dst[eu]);
        float v = hs[(size_t)s * HID + lane] * dinv[d];
        atomicAdd(&acc1[(size_t)d * HID + lane], v);
    }
}

__global__ __launch_bounds__(256) void k_seed2(const float* __restrict__ h2s,
                                               const float* __restrict__ dinv,
                                               const float* __restrict__ b2,
                                               float* __restrict__ out) {
    int idx = blockIdx.x * 256 + threadIdx.x;  // over NN*CLS
    if (idx < NN * CLS) {
        int r = idx / CLS, c = idx - r * CLS;
        out[idx] = h2s[idx] * dinv[r] + b2[c];
    }
}

__global__ __launch_bounds__(256) void k_scatter2(const int* __restrict__ src,
                                                  const int* __restrict__ dst,
                                                  const float* __restrict__ dinv,
                                                  const float* __restrict__ h2s,
                                                  float* __restrict__ out) {
    const unsigned total = (unsigned)EE * CLS;
    unsigned stride = gridDim.x * 256u;
    for (unsigned idx = blockIdx.x * 256u + threadIdx.x; idx < total; idx += stride) {
        unsigned e = idx / CLS;
        unsigned c = idx - e * CLS;
        int s = src[e];
        int d = dst[e];
        float v = h2s[(size_t)s * CLS + c] * dinv[d];
        atomicAdd(&out[(size_t)d * CLS + c], v);
    }
}

// ===========================================================================
// Launch
// ===========================================================================
extern "C" void kernel_launch(void* const* d_in, const int* in_sizes, int n_in,
                              void* d_out, int out_size, void* d_ws, size_t ws_size,
                              hipStream_t stream) {
    const float* x   = (const float*)d_in[0];
    const float* W1  = (const float*)d_in[1];
    const float* b1  = (const float*)d_in[2];
    const float* W2  = (const float*)d_in[3];
    const float* b2  = (const float*)d_in[4];
    const int*   edg = (const int*)d_in[5];
    const int* src = edg;        // edges[0][:]
    const int* dst = edg + EE;   // edges[1][:]
    float* out = (float*)d_out;
    char* ws = (char*)d_ws;

    const int nb_n = NB_N;               // 391
    const int nb_e = (EE + 255) / 256;   // 6250

    // CSR-path workspace layout:
    //   deg   @ 0         (512 KB)   rowp @ 512K   dinv @ 1M   bsum @ 1.5M
    //   boff  @ 1.75M     csr  @ 2M  (6.4 MB)
    //   hs    @ 10M       (25.6 MB; reused as h2s [16 MB] after agg1)
    //   acc1  @ 36M       (25.6 MB; first 400 KB doubles as cursor pre-agg1)
    const size_t NEED = (size_t)(36 << 20) + (size_t)NN * HID * 4;  // ~60.4 MB

    if (ws_size >= NEED) {
        int*   deg    = (int*)(ws);
        int*   rowp   = (int*)(ws + (512 << 10));
        float* dinv   = (float*)(ws + (1 << 20));
        int*   bsum   = (int*)(ws + ((1 << 20) + (512 << 10)));
        int*   boff   = (int*)(ws + ((1 << 20) + (768 << 10)));
        int*   csr    = (int*)(ws + (2 << 20));
        float* hs     = (float*)(ws + (10 << 20));
        float* acc1   = (float*)(ws + (36 << 20));
        int*   cursor = (int*)acc1;     // dead before agg1 writes acc1
        float* h2s    = hs;             // hs dead after agg1

        k_zero<<<nb_n, 256, 0, stream>>>(deg);
        k_count<<<nb_e, 256, 0, stream>>>(dst, deg);
        k_scan_bsum<<<nb_n, 256, 0, stream>>>(deg, bsum);
        k_scan_boff<<<1, 512, 0, stream>>>(bsum, boff);
        k_scan_fin<<<nb_n, 256, 0, stream>>>(deg, boff, rowp, cursor, dinv);
        k_fill<<<nb_e, 256, 0, stream>>>(src, dst, cursor, csr);

        k_gemm1<<<(NN + 63) / 64, 256, 0, stream>>>(x, W1, dinv, hs);
        k_agg1<<<(NN + 3) / 4, 256, 0, stream>>>(rowp, deg, csr, dinv, b1, hs, acc1);
        k_gemm2<<<(NN + 127) / 128, 256, 0, stream>>>(acc1, W2, dinv, h2s);
        k_agg2<<<(NN + 3) / 4, 256, 0, stream>>>(rowp, deg, csr, dinv, b2, h2s, out);
    } else {
        // Fallback: atomic scatter (round-2 design), ~53 MB
        int*   deg  = (int*)(ws);
        float* dinv = (float*)(ws + (512 << 10));
        float* hs   = (float*)(ws + (1 << 20));
        float* acc1 = (float*)(ws + (1 << 20) + (size_t)NN * HID * 4);
        float* h2s  = hs;

        k_zero<<<nb_n, 256, 0, stream>>>(deg);
        k_count<<<nb_e, 256, 0, stream>>>(dst, deg);
        k_dinv<<<nb_n, 256, 0, stream>>>(deg, dinv);

        k_gemm1<<<(NN + 63) / 64, 256, 0, stream>>>(x, W1, dinv, hs);
        k_seed1<<<(NN * HID + 255) / 256, 256, 0, stream>>>(hs, dinv, b1, acc1);
        k_scatter1<<<8192, 256, 0, stream>>>(src, dst, dinv, hs, acc1);
        k_gemm2<<<(NN + 127) / 128, 256, 0, stream>>>(acc1, W2, dinv, h2s);
        k_seed2<<<(NN * CLS + 255) / 256, 256, 0, stream>>>(h2s, dinv, b2, out);
        k_scatter2<<<8192, 256, 0, stream>>>(src, dst, dinv, h2s, out);
    }
}

// Round 6
// 597.960 us; speedup vs baseline: 1.7102x; 1.0196x over previous
//
#include <hip/hip_runtime.h>
#include <math.h>

// Problem constants (from reference)
#define NN 100000
#define EE 1600000
#define FIN 256
#define HID 64
#define CLS 40
#define NB_N 391  // ceil(NN/256)

// ===========================================================================
// CSR build: deg -> exclusive scan -> cursor fill.  All int.
// ===========================================================================
__global__ __launch_bounds__(256) void k_zero(int* __restrict__ deg) {
    int n = blockIdx.x * 256 + threadIdx.x;
    if (n < NN) deg[n] = 0;
}

__global__ __launch_bounds__(256) void k_count(const int* __restrict__ dst,
                                               int* __restrict__ deg) {
    int e = blockIdx.x * 256 + threadIdx.x;
    if (e < EE) atomicAdd(&deg[dst[e]], 1);
}

// block sums of 256-wide tiles
__global__ __launch_bounds__(256) void k_scan_bsum(const int* __restrict__ deg,
                                                   int* __restrict__ bsum) {
    __shared__ int sm[256];
    int t = threadIdx.x;
    int n = blockIdx.x * 256 + t;
    sm[t] = (n < NN) ? deg[n] : 0;
    __syncthreads();
    for (int off = 128; off > 0; off >>= 1) {
        if (t < off) sm[t] += sm[t + off];
        __syncthreads();
    }
    if (t == 0) bsum[blockIdx.x] = sm[0];
}

// exclusive scan of NB_N block sums (single block, 512 threads)
__global__ __launch_bounds__(512) void k_scan_boff(const int* __restrict__ bsum,
                                                   int* __restrict__ boff) {
    __shared__ int sm[512];
    int t = threadIdx.x;
    int v = (t < NB_N) ? bsum[t] : 0;
    sm[t] = v;
    __syncthreads();
    for (int off = 1; off < 512; off <<= 1) {
        int u = (t >= off) ? sm[t - off] : 0;
        __syncthreads();
        sm[t] += u;
        __syncthreads();
    }
    if (t < NB_N) boff[t] = sm[t] - v;  // exclusive
}

// local exclusive scan + block offset -> row_ptr & fill cursor; also dinv
__global__ __launch_bounds__(256) void k_scan_fin(const int* __restrict__ deg,
                                                  const int* __restrict__ boff,
                                                  int* __restrict__ rowp,
                                                  int* __restrict__ cursor,
                                                  float* __restrict__ dinv) {
    __shared__ int sm[256];
    int t = threadIdx.x;
    int n = blockIdx.x * 256 + t;
    int v = (n < NN) ? deg[n] : 0;
    sm[t] = v;
    __syncthreads();
    for (int off = 1; off < 256; off <<= 1) {
        int u = (t >= off) ? sm[t - off] : 0;
        __syncthreads();
        sm[t] += u;
        __syncthreads();
    }
    if (n < NN) {
        int start = boff[blockIdx.x] + sm[t] - v;
        rowp[n] = start;
        cursor[n] = start;
        dinv[n] = rsqrtf((float)(v + 1));  // +1 self loop
    }
}

__global__ __launch_bounds__(256) void k_fill(const int* __restrict__ src,
                                              const int* __restrict__ dst,
                                              int* __restrict__ cursor,
                                              int* __restrict__ csr) {
    int e = blockIdx.x * 256 + threadIdx.x;
    if (e < EE) {
        int d = dst[e];
        int pos = atomicAdd(&cursor[d], 1);
        csr[pos] = src[e];
    }
}

// ===========================================================================
// GEMM1 v3: hs = (x @ W1) * dinv[r]   [100000x256 @ 256x64]
// One WAVE per 8 rows (100000 = 8*12500 exactly -> no tail). lane = column.
// x addresses are wave-uniform (readfirstlane'd wave id) -> scalar s_load
// through the SMEM pipe; W1 row reads are coalesced 256B VMEM (dword/lane).
// FMA:VMEM = 8:1, acc = 8 VGPR -> 8 waves/SIMD; grid 3125 = 12.2 blocks/CU.
// ===========================================================================
__global__ __launch_bounds__(256) void k_gemm1(const float* __restrict__ x,
                                               const float* __restrict__ W1,
                                               const float* __restrict__ dinv,
                                               float* __restrict__ hs) {
    int lane = threadIdx.x & 63;
    int wid = __builtin_amdgcn_readfirstlane(
        (int)(blockIdx.x * 4 + (threadIdx.x >> 6)));
    int r0 = wid * 8;  // always < NN (exact fit)

    const float* xr = x + (size_t)r0 * FIN;

    float acc[8];
#pragma unroll
    for (int i = 0; i < 8; i++) acc[i] = 0.0f;

#pragma unroll 2
    for (int k = 0; k < FIN; k += 4) {
        float4 xs[8];
#pragma unroll
        for (int i = 0; i < 8; i++)
            xs[i] = *(const float4*)&xr[(size_t)i * FIN + k];  // uniform -> s_load
#pragma unroll
        for (int kk = 0; kk < 4; kk++) {
            float w = W1[(k + kk) * HID + lane];  // coalesced 256B/wave
#pragma unroll
            for (int i = 0; i < 8; i++) {
                float xv = (kk == 0) ? xs[i].x : (kk == 1) ? xs[i].y
                         : (kk == 2) ? xs[i].z : xs[i].w;
                acc[i] += xv * w;
            }
        }
    }

#pragma unroll
    for (int i = 0; i < 8; i++) {
        float di = dinv[r0 + i];  // uniform -> s_load
        hs[(size_t)(r0 + i) * HID + lane] = acc[i] * di;
    }
}

// ===========================================================================
// agg1: acc1[d][c] = relu((hs[d][c] + sum_{e in CSR[d]} hs[src_e][c])
//                        * dinv[d] + b1[c])
// ReLU fused here (acc1 is only ever consumed as relu(acc1) by gemm2).
// One WAVE per node, 64 lanes = 64 channels. Unroll-8 keeps 8 gathers in
// flight (mean degree 16). csr/rowp/deg loads wave-uniform -> scalar.
// ===========================================================================
__global__ __launch_bounds__(256) void k_agg1(const int* __restrict__ rowp,
                                              const int* __restrict__ deg,
                                              const int* __restrict__ csr,
                                              const float* __restrict__ dinv,
                                              const float* __restrict__ b1,
                                              const float* __restrict__ hs,
                                              float* __restrict__ acc1) {
    int lane = threadIdx.x & 63;
    int n = blockIdx.x * 4 + (threadIdx.x >> 6);
    if (n >= NN) return;
    int rp  = __builtin_amdgcn_readfirstlane(rowp[n]);
    int cnt = __builtin_amdgcn_readfirstlane(deg[n]);

    float acc = hs[(size_t)n * HID + lane];  // self loop
    int e = 0;
    for (; e + 8 <= cnt; e += 8) {
        int s0 = __builtin_amdgcn_readfirstlane(csr[rp + e]);
        int s1 = __builtin_amdgcn_readfirstlane(csr[rp + e + 1]);
        int s2 = __builtin_amdgcn_readfirstlane(csr[rp + e + 2]);
        int s3 = __builtin_amdgcn_readfirstlane(csr[rp + e + 3]);
        int s4 = __builtin_amdgcn_readfirstlane(csr[rp + e + 4]);
        int s5 = __builtin_amdgcn_readfirstlane(csr[rp + e + 5]);
        int s6 = __builtin_amdgcn_readfirstlane(csr[rp + e + 6]);
        int s7 = __builtin_amdgcn_readfirstlane(csr[rp + e + 7]);
        float v0 = hs[(size_t)s0 * HID + lane];
        float v1 = hs[(size_t)s1 * HID + lane];
        float v2 = hs[(size_t)s2 * HID + lane];
        float v3 = hs[(size_t)s3 * HID + lane];
        float v4 = hs[(size_t)s4 * HID + lane];
        float v5 = hs[(size_t)s5 * HID + lane];
        float v6 = hs[(size_t)s6 * HID + lane];
        float v7 = hs[(size_t)s7 * HID + lane];
        acc += ((v0 + v1) + (v2 + v3)) + ((v4 + v5) + (v6 + v7));
    }
    for (; e + 4 <= cnt; e += 4) {
        int s0 = __builtin_amdgcn_readfirstlane(csr[rp + e]);
        int s1 = __builtin_amdgcn_readfirstlane(csr[rp + e + 1]);
        int s2 = __builtin_amdgcn_readfirstlane(csr[rp + e + 2]);
        int s3 = __builtin_amdgcn_readfirstlane(csr[rp + e + 3]);
        float v0 = hs[(size_t)s0 * HID + lane];
        float v1 = hs[(size_t)s1 * HID + lane];
        float v2 = hs[(size_t)s2 * HID + lane];
        float v3 = hs[(size_t)s3 * HID + lane];
        acc += (v0 + v1) + (v2 + v3);
    }
    for (; e < cnt; e++) {
        int s = __builtin_amdgcn_readfirstlane(csr[rp + e]);
        acc += hs[(size_t)s * HID + lane];
    }
    acc1[(size_t)n * HID + lane] = fmaxf(acc * dinv[n] + b1[lane], 0.0f);
}

// ===========================================================================
// GEMM2 v2: h2s = (acc1 @ W2) * dinv[r]   [100000x64 @ 64x40]
// (acc1 is already ReLU'd by agg1.)  Same structure as GEMM1 v3: one wave
// per 8 rows, lane = column (clamped to CLS-1 for lanes >= 40, masked store).
// x-side reads scalar (uniform), W2 reads coalesced VMEM, grid 3125.
// ===========================================================================
__global__ __launch_bounds__(256) void k_gemm2(const float* __restrict__ acc1,
                                               const float* __restrict__ W2,
                                               const float* __restrict__ dinv,
                                               float* __restrict__ h2s) {
    int lane = threadIdx.x & 63;
    int cl = lane < CLS ? lane : CLS - 1;
    int wid = __builtin_amdgcn_readfirstlane(
        (int)(blockIdx.x * 4 + (threadIdx.x >> 6)));
    int r0 = wid * 8;  // exact fit

    const float* xr = acc1 + (size_t)r0 * HID;

    float acc[8];
#pragma unroll
    for (int i = 0; i < 8; i++) acc[i] = 0.0f;

#pragma unroll 2
    for (int k = 0; k < HID; k += 4) {
        float4 xs[8];
#pragma unroll
        for (int i = 0; i < 8; i++)
            xs[i] = *(const float4*)&xr[(size_t)i * HID + k];  // uniform -> s_load
#pragma unroll
        for (int kk = 0; kk < 4; kk++) {
            float w = W2[(k + kk) * CLS + cl];
#pragma unroll
            for (int i = 0; i < 8; i++) {
                float xv = (kk == 0) ? xs[i].x : (kk == 1) ? xs[i].y
                         : (kk == 2) ? xs[i].z : xs[i].w;
                acc[i] += xv * w;
            }
        }
    }

    if (lane < CLS) {
#pragma unroll
        for (int i = 0; i < 8; i++) {
            float di = dinv[r0 + i];
            h2s[(size_t)(r0 + i) * CLS + lane] = acc[i] * di;
        }
    }
}

// ===========================================================================
// agg2: out[d][c] = (h2s[d][c] + sum_e h2s[src_e][c]) * dinv[d] + b2[c]
// One WAVE per node; lanes >= CLS read clamped addr (broadcast), masked store.
// Unroll-8 like agg1.
// ===========================================================================
__global__ __launch_bounds__(256) void k_agg2(const int* __restrict__ rowp,
                                              const int* __restrict__ deg,
                                              const int* __restrict__ csr,
                                              const float* __restrict__ dinv,
                                              const float* __restrict__ b2,
                                              const float* __restrict__ h2s,
                                              float* __restrict__ out) {
    int lane = threadIdx.x & 63;
    int cl = lane < CLS ? lane : CLS - 1;
    int n = blockIdx.x * 4 + (threadIdx.x >> 6);
    if (n >= NN) return;
    int rp  = __builtin_amdgcn_readfirstlane(rowp[n]);
    int cnt = __builtin_amdgcn_readfirstlane(deg[n]);

    float acc = h2s[(size_t)n * CLS + cl];  // self loop
    int e = 0;
    for (; e + 8 <= cnt; e += 8) {
        int s0 = __builtin_amdgcn_readfirstlane(csr[rp + e]);
        int s1 = __builtin_amdgcn_readfirstlane(csr[rp + e + 1]);
        int s2 = __builtin_amdgcn_readfirstlane(csr[rp + e + 2]);
        int s3 = __builtin_amdgcn_readfirstlane(csr[rp + e + 3]);
        int s4 = __builtin_amdgcn_readfirstlane(csr[rp + e + 4]);
        int s5 = __builtin_amdgcn_readfirstlane(csr[rp + e + 5]);
        int s6 = __builtin_amdgcn_readfirstlane(csr[rp + e + 6]);
        int s7 = __builtin_amdgcn_readfirstlane(csr[rp + e + 7]);
        float v0 = h2s[(size_t)s0 * CLS + cl];
        float v1 = h2s[(size_t)s1 * CLS + cl];
        float v2 = h2s[(size_t)s2 * CLS + cl];
        float v3 = h2s[(size_t)s3 * CLS + cl];
        float v4 = h2s[(size_t)s4 * CLS + cl];
        float v5 = h2s[(size_t)s5 * CLS + cl];
        float v6 = h2s[(size_t)s6 * CLS + cl];
        float v7 = h2s[(size_t)s7 * CLS + cl];
        acc += ((v0 + v1) + (v2 + v3)) + ((v4 + v5) + (v6 + v7));
    }
    for (; e + 4 <= cnt; e += 4) {
        int s0 = __builtin_amdgcn_readfirstlane(csr[rp + e]);
        int s1 = __builtin_amdgcn_readfirstlane(csr[rp + e + 1]);
        int s2 = __builtin_amdgcn_readfirstlane(csr[rp + e + 2]);
        int s3 = __builtin_amdgcn_readfirstlane(csr[rp + e + 3]);
        float v0 = h2s[(size_t)s0 * CLS + cl];
        float v1 = h2s[(size_t)s1 * CLS + cl];
        float v2 = h2s[(size_t)s2 * CLS + cl];
        float v3 = h2s[(size_t)s3 * CLS + cl];
        acc += (v0 + v1) + (v2 + v3);
    }
    for (; e < cnt; e++) {
        int s = __builtin_amdgcn_readfirstlane(csr[rp + e]);
        acc += h2s[(size_t)s * CLS + cl];
    }
    if (lane < CLS)
        out[(size_t)n * CLS + lane] = acc * dinv[n] + b2[lane];
}

// ===========================================================================
// Launch
// ===========================================================================
extern "C" void kernel_launch(void* const* d_in, const int* in_sizes, int n_in,
                              void* d_out, int out_size, void* d_ws, size_t ws_size,
                              hipStream_t stream) {
    const float* x   = (const float*)d_in[0];
    const float* W1  = (const float*)d_in[1];
    const float* b1  = (const float*)d_in[2];
    const float* W2  = (const float*)d_in[3];
    const float* b2  = (const float*)d_in[4];
    const int*   edg = (const int*)d_in[5];
    const int* src = edg;        // edges[0][:]
    const int* dst = edg + EE;   // edges[1][:]
    float* out = (float*)d_out;
    char* ws = (char*)d_ws;

    const int nb_n = NB_N;               // 391
    const int nb_e = (EE + 255) / 256;   // 6250

    // Workspace layout (CSR path; proven sufficient in rounds 4-5):
    //   deg   @ 0         (512 KB)   rowp @ 512K   dinv @ 1M   bsum @ 1.5M
    //   boff  @ 1.75M     csr  @ 2M  (6.4 MB)
    //   hs    @ 10M       (25.6 MB; reused as h2s [16 MB] after agg1)
    //   acc1  @ 36M       (25.6 MB; first 400 KB doubles as cursor pre-agg1)
    int*   deg    = (int*)(ws);
    int*   rowp   = (int*)(ws + (512 << 10));
    float* dinv   = (float*)(ws + (1 << 20));
    int*   bsum   = (int*)(ws + ((1 << 20) + (512 << 10)));
    int*   boff   = (int*)(ws + ((1 << 20) + (768 << 10)));
    int*   csr    = (int*)(ws + (2 << 20));
    float* hs     = (float*)(ws + (10 << 20));
    float* acc1   = (float*)(ws + (36 << 20));
    int*   cursor = (int*)acc1;     // dead before agg1 writes acc1
    float* h2s    = hs;             // hs dead after agg1

    k_zero<<<nb_n, 256, 0, stream>>>(deg);
    k_count<<<nb_e, 256, 0, stream>>>(dst, deg);
    k_scan_bsum<<<nb_n, 256, 0, stream>>>(deg, bsum);
    k_scan_boff<<<1, 512, 0, stream>>>(bsum, boff);
    k_scan_fin<<<nb_n, 256, 0, stream>>>(deg, boff, rowp, cursor, dinv);
    k_fill<<<nb_e, 256, 0, stream>>>(src, dst, cursor, csr);

    k_gemm1<<<3125, 256, 0, stream>>>(x, W1, dinv, hs);           // 12500 waves
    k_agg1<<<(NN + 3) / 4, 256, 0, stream>>>(rowp, deg, csr, dinv, b1, hs, acc1);
    k_gemm2<<<3125, 256, 0, stream>>>(acc1, W2, dinv, h2s);       // 12500 waves
    k_agg2<<<(NN + 3) / 4, 256, 0, stream>>>(rowp, deg, csr, dinv, b2, h2s, out);
}

// Round 10
// 527.796 us; speedup vs baseline: 1.9375x; 1.1329x over previous
//
#include <hip/hip_runtime.h>
#include <math.h>

// Problem constants (from reference)
#define NN 100000
#define EE 1600000
#define FIN 256
#define HID 64
#define CLS 40
#define NB_N 391  // ceil(NN/256)

// ===========================================================================
// CSR build: deg -> exclusive scan -> cursor fill.  All int.
// ===========================================================================
__global__ __launch_bounds__(256) void k_zero(int* __restrict__ deg) {
    int n = blockIdx.x * 256 + threadIdx.x;
    if (n < NN) deg[n] = 0;
}

__global__ __launch_bounds__(256) void k_count(const int* __restrict__ dst,
                                               int* __restrict__ deg) {
    int e = blockIdx.x * 256 + threadIdx.x;
    if (e < EE) atomicAdd(&deg[dst[e]], 1);
}

// block sums of 256-wide tiles
__global__ __launch_bounds__(256) void k_scan_bsum(const int* __restrict__ deg,
                                                   int* __restrict__ bsum) {
    __shared__ int sm[256];
    int t = threadIdx.x;
    int n = blockIdx.x * 256 + t;
    sm[t] = (n < NN) ? deg[n] : 0;
    __syncthreads();
    for (int off = 128; off > 0; off >>= 1) {
        if (t < off) sm[t] += sm[t + off];
        __syncthreads();
    }
    if (t == 0) bsum[blockIdx.x] = sm[0];
}

// exclusive scan of NB_N block sums (single block, 512 threads)
__global__ __launch_bounds__(512) void k_scan_boff(const int* __restrict__ bsum,
                                                   int* __restrict__ boff) {
    __shared__ int sm[512];
    int t = threadIdx.x;
    int v = (t < NB_N) ? bsum[t] : 0;
    sm[t] = v;
    __syncthreads();
    for (int off = 1; off < 512; off <<= 1) {
        int u = (t >= off) ? sm[t - off] : 0;
        __syncthreads();
        sm[t] += u;
        __syncthreads();
    }
    if (t < NB_N) boff[t] = sm[t] - v;  // exclusive
}

// local exclusive scan + block offset -> row_ptr & fill cursor; also dinv
__global__ __launch_bounds__(256) void k_scan_fin(const int* __restrict__ deg,
                                                  const int* __restrict__ boff,
                                                  int* __restrict__ rowp,
                                                  int* __restrict__ cursor,
                                                  float* __restrict__ dinv) {
    __shared__ int sm[256];
    int t = threadIdx.x;
    int n = blockIdx.x * 256 + t;
    int v = (n < NN) ? deg[n] : 0;
    sm[t] = v;
    __syncthreads();
    for (int off = 1; off < 256; off <<= 1) {
        int u = (t >= off) ? sm[t - off] : 0;
        __syncthreads();
        sm[t] += u;
        __syncthreads();
    }
    if (n < NN) {
        int start = boff[blockIdx.x] + sm[t] - v;
        rowp[n] = start;
        cursor[n] = start;
        dinv[n] = rsqrtf((float)(v + 1));  // +1 self loop
    }
}

__global__ __launch_bounds__(256) void k_fill(const int* __restrict__ src,
                                              const int* __restrict__ dst,
                                              int* __restrict__ cursor,
                                              int* __restrict__ csr) {
    int e = blockIdx.x * 256 + threadIdx.x;
    if (e < EE) {
        int d = dst[e];
        int pos = atomicAdd(&cursor[d], 1);
        csr[pos] = src[e];
    }
}

// ===========================================================================
// GEMM1 v4: hs = (x @ W1) * dinv[r]   [100000x256 @ 256x64]
// Latency fix for v3 (165us @ 23% VALU): each wave stages its ENTIRE 8-row
// x panel (8 KB contiguous) into a wave-private LDS slice with 8 independent
// float4 loads in flight (16x the in-flight bytes of v3; one wait total),
// then the k-loop reads x via same-address LDS broadcasts (conflict-free)
// and W1 via explicitly double-buffered coalesced loads (L2-hot, prefetched
// one k-step ahead). No __syncthreads needed (wave-private slices).
// 32 KB LDS/block -> 5 blocks/CU -> 20 waves/CU.
// ===========================================================================
__global__ __launch_bounds__(256) void k_gemm1(const float* __restrict__ x,
                                               const float* __restrict__ W1,
                                               const float* __restrict__ dinv,
                                               float* __restrict__ hs) {
    __shared__ float sm[4][8 * FIN];  // 4 waves x 8 KB
    int tid = threadIdx.x;
    int lane = tid & 63;
    int w = tid >> 6;
    int wid = blockIdx.x * 4 + w;  // 0..12499 (exact: 100000 = 8*12500)
    int r0 = wid * 8;

    float* xw = sm[w];

    // ---- stage: 8 rows x 256 floats = 8192 B contiguous, 8 loads in flight
    {
        const float* xbase = x + (size_t)r0 * FIN;
        float4 t[8];
#pragma unroll
        for (int i = 0; i < 8; i++)
            t[i] = *(const float4*)&xbase[i * 256 + lane * 4];  // 1 KB/instr
#pragma unroll
        for (int i = 0; i < 8; i++)
            *(float4*)&xw[i * 256 + lane * 4] = t[i];
    }
    __builtin_amdgcn_sched_barrier(0);  // keep stage before k-loop reads

    float acc[8];
#pragma unroll
    for (int i = 0; i < 8; i++) acc[i] = 0.0f;

    float wA[4], wB[4];
#pragma unroll
    for (int j = 0; j < 4; j++) wA[j] = W1[j * HID + lane];  // k=0..3

    for (int k = 0; k < FIN; k += 8) {
        // prefetch W for k+4..k+7
#pragma unroll
        for (int j = 0; j < 4; j++) wB[j] = W1[(k + 4 + j) * HID + lane];
        {
            float4 xv[8];
#pragma unroll
            for (int i = 0; i < 8; i++)
                xv[i] = *(const float4*)&xw[i * 256 + k];  // broadcast
#pragma unroll
            for (int kk = 0; kk < 4; kk++)
#pragma unroll
                for (int i = 0; i < 8; i++) {
                    float xv_s = (kk == 0) ? xv[i].x : (kk == 1) ? xv[i].y
                               : (kk == 2) ? xv[i].z : xv[i].w;
                    acc[i] += xv_s * wA[kk];
                }
        }
        // prefetch W for k+8..k+11 (guarded; last iter re-reads k=252 harmlessly)
        int kb = (k + 8 < FIN) ? (k + 8) : (FIN - 4);
#pragma unroll
        for (int j = 0; j < 4; j++) wA[j] = W1[(kb + j) * HID + lane];
        {
            float4 xv[8];
#pragma unroll
            for (int i = 0; i < 8; i++)
                xv[i] = *(const float4*)&xw[i * 256 + k + 4];  // broadcast
#pragma unroll
            for (int kk = 0; kk < 4; kk++)
#pragma unroll
                for (int i = 0; i < 8; i++) {
                    float xv_s = (kk == 0) ? xv[i].x : (kk == 1) ? xv[i].y
                               : (kk == 2) ? xv[i].z : xv[i].w;
                    acc[i] += xv_s * wB[kk];
                }
        }
    }

#pragma unroll
    for (int i = 0; i < 8; i++) {
        float di = dinv[r0 + i];  // uniform -> scalar
        hs[(size_t)(r0 + i) * HID + lane] = acc[i] * di;
    }
}

// ===========================================================================
// agg1: acc1[d][c] = relu((hs[d][c] + sum_{e in CSR[d]} hs[src_e][c])
//                        * dinv[d] + b1[c])
// One WAVE per node, 64 lanes = 64 channels. Unroll-8 gathers in flight.
// ===========================================================================
__global__ __launch_bounds__(256) void k_agg1(const int* __restrict__ rowp,
                                              const int* __restrict__ deg,
                                              const int* __restrict__ csr,
                                              const float* __restrict__ dinv,
                                              const float* __restrict__ b1,
                                              const float* __restrict__ hs,
                                              float* __restrict__ acc1) {
    int lane = threadIdx.x & 63;
    int n = blockIdx.x * 4 + (threadIdx.x >> 6);
    if (n >= NN) return;
    int rp  = __builtin_amdgcn_readfirstlane(rowp[n]);
    int cnt = __builtin_amdgcn_readfirstlane(deg[n]);

    float acc = hs[(size_t)n * HID + lane];  // self loop
    int e = 0;
    for (; e + 8 <= cnt; e += 8) {
        int s0 = __builtin_amdgcn_readfirstlane(csr[rp + e]);
        int s1 = __builtin_amdgcn_readfirstlane(csr[rp + e + 1]);
        int s2 = __builtin_amdgcn_readfirstlane(csr[rp + e + 2]);
        int s3 = __builtin_amdgcn_readfirstlane(csr[rp + e + 3]);
        int s4 = __builtin_amdgcn_readfirstlane(csr[rp + e + 4]);
        int s5 = __builtin_amdgcn_readfirstlane(csr[rp + e + 5]);
        int s6 = __builtin_amdgcn_readfirstlane(csr[rp + e + 6]);
        int s7 = __builtin_amdgcn_readfirstlane(csr[rp + e + 7]);
        float v0 = hs[(size_t)s0 * HID + lane];
        float v1 = hs[(size_t)s1 * HID + lane];
        float v2 = hs[(size_t)s2 * HID + lane];
        float v3 = hs[(size_t)s3 * HID + lane];
        float v4 = hs[(size_t)s4 * HID + lane];
        float v5 = hs[(size_t)s5 * HID + lane];
        float v6 = hs[(size_t)s6 * HID + lane];
        float v7 = hs[(size_t)s7 * HID + lane];
        acc += ((v0 + v1) + (v2 + v3)) + ((v4 + v5) + (v6 + v7));
    }
    for (; e + 4 <= cnt; e += 4) {
        int s0 = __builtin_amdgcn_readfirstlane(csr[rp + e]);
        int s1 = __builtin_amdgcn_readfirstlane(csr[rp + e + 1]);
        int s2 = __builtin_amdgcn_readfirstlane(csr[rp + e + 2]);
        int s3 = __builtin_amdgcn_readfirstlane(csr[rp + e + 3]);
        float v0 = hs[(size_t)s0 * HID + lane];
        float v1 = hs[(size_t)s1 * HID + lane];
        float v2 = hs[(size_t)s2 * HID + lane];
        float v3 = hs[(size_t)s3 * HID + lane];
        acc += (v0 + v1) + (v2 + v3);
    }
    for (; e < cnt; e++) {
        int s = __builtin_amdgcn_readfirstlane(csr[rp + e]);
        acc += hs[(size_t)s * HID + lane];
    }
    acc1[(size_t)n * HID + lane] = fmaxf(acc * dinv[n] + b1[lane], 0.0f);
}

// ===========================================================================
// GEMM2 v3: h2s = (acc1 @ W2) * dinv[r]   [100000x64 @ 64x40]
// Same template as GEMM1 v4: 2 KB wave-private stage (2 loads in flight),
// LDS broadcast k-loop, double-buffered W2. Lane clamped to CLS-1 for the
// W2 read; store masked to lane<CLS. 8 KB LDS/block.
// ===========================================================================
__global__ __launch_bounds__(256) void k_gemm2(const float* __restrict__ acc1,
                                               const float* __restrict__ W2,
                                               const float* __restrict__ dinv,
                                               float* __restrict__ h2s) {
    __shared__ float sm[4][8 * HID];  // 4 waves x 2 KB
    int tid = threadIdx.x;
    int lane = tid & 63;
    int cl = lane < CLS ? lane : CLS - 1;
    int w = tid >> 6;
    int wid = blockIdx.x * 4 + w;
    int r0 = wid * 8;  // exact fit

    float* xw = sm[w];

    // ---- stage: 8 rows x 64 floats = 2048 B contiguous, 2 loads in flight
    {
        const float* xbase = acc1 + (size_t)r0 * HID;
        float4 t0 = *(const float4*)&xbase[lane * 4];        // floats 0..255
        float4 t1 = *(const float4*)&xbase[256 + lane * 4];  // floats 256..511
        *(float4*)&xw[lane * 4] = t0;
        *(float4*)&xw[256 + lane * 4] = t1;
    }
    __builtin_amdgcn_sched_barrier(0);

    float acc[8];
#pragma unroll
    for (int i = 0; i < 8; i++) acc[i] = 0.0f;

    float wA[4], wB[4];
#pragma unroll
    for (int j = 0; j < 4; j++) wA[j] = W2[j * CLS + cl];

    for (int k = 0; k < HID; k += 8) {
#pragma unroll
        for (int j = 0; j < 4; j++) wB[j] = W2[(k + 4 + j) * CLS + cl];
        {
            float4 xv[8];
#pragma unroll
            for (int i = 0; i < 8; i++)
                xv[i] = *(const float4*)&xw[i * 64 + k];  // broadcast
#pragma unroll
            for (int kk = 0; kk < 4; kk++)
#pragma unroll
                for (int i = 0; i < 8; i++) {
                    float xv_s = (kk == 0) ? xv[i].x : (kk == 1) ? xv[i].y
                               : (kk == 2) ? xv[i].z : xv[i].w;
                    acc[i] += xv_s * wA[kk];
                }
        }
        int kb = (k + 8 < HID) ? (k + 8) : (HID - 4);
#pragma unroll
        for (int j = 0; j < 4; j++) wA[j] = W2[(kb + j) * CLS + cl];
        {
            float4 xv[8];
#pragma unroll
            for (int i = 0; i < 8; i++)
                xv[i] = *(const float4*)&xw[i * 64 + k + 4];  // broadcast
#pragma unroll
            for (int kk = 0; kk < 4; kk++)
#pragma unroll
                for (int i = 0; i < 8; i++) {
                    float xv_s = (kk == 0) ? xv[i].x : (kk == 1) ? xv[i].y
                               : (kk == 2) ? xv[i].z : xv[i].w;
                    acc[i] += xv_s * wB[kk];
                }
        }
    }

    if (lane < CLS) {
#pragma unroll
        for (int i = 0; i < 8; i++) {
            float di = dinv[r0 + i];
            h2s[(size_t)(r0 + i) * CLS + lane] = acc[i] * di;
        }
    }
}

// ===========================================================================
// agg2: out[d][c] = (h2s[d][c] + sum_e h2s[src_e][c]) * dinv[d] + b2[c]
// One WAVE per node; lanes >= CLS read clamped addr (broadcast), masked store.
// ===========================================================================
__global__ __launch_bounds__(256) void k_agg2(const int* __restrict__ rowp,
                                              const int* __restrict__ deg,
                                              const int* __restrict__ csr,
                                              const float* __restrict__ dinv,
                                              const float* __restrict__ b2,
                                              const float* __restrict__ h2s,
                                              float* __restrict__ out) {
    int lane = threadIdx.x & 63;
    int cl = lane < CLS ? lane : CLS - 1;
    int n = blockIdx.x * 4 + (threadIdx.x >> 6);
    if (n >= NN) return;
    int rp  = __builtin_amdgcn_readfirstlane(rowp[n]);
    int cnt = __builtin_amdgcn_readfirstlane(deg[n]);

    float acc = h2s[(size_t)n * CLS + cl];  // self loop
    int e = 0;
    for (; e + 8 <= cnt; e += 8) {
        int s0 = __builtin_amdgcn_readfirstlane(csr[rp + e]);
        int s1 = __builtin_amdgcn_readfirstlane(csr[rp + e + 1]);
        int s2 = __builtin_amdgcn_readfirstlane(csr[rp + e + 2]);
        int s3 = __builtin_amdgcn_readfirstlane(csr[rp + e + 3]);
        int s4 = __builtin_amdgcn_readfirstlane(csr[rp + e + 4]);
        int s5 = __builtin_amdgcn_readfirstlane(csr[rp + e + 5]);
        int s6 = __builtin_amdgcn_readfirstlane(csr[rp + e + 6]);
        int s7 = __builtin_amdgcn_readfirstlane(csr[rp + e + 7]);
        float v0 = h2s[(size_t)s0 * CLS + cl];
        float v1 = h2s[(size_t)s1 * CLS + cl];
        float v2 = h2s[(size_t)s2 * CLS + cl];
        float v3 = h2s[(size_t)s3 * CLS + cl];
        float v4 = h2s[(size_t)s4 * CLS + cl];
        float v5 = h2s[(size_t)s5 * CLS + cl];
        float v6 = h2s[(size_t)s6 * CLS + cl];
        float v7 = h2s[(size_t)s7 * CLS + cl];
        acc += ((v0 + v1) + (v2 + v3)) + ((v4 + v5) + (v6 + v7));
    }
    for (; e + 4 <= cnt; e += 4) {
        int s0 = __builtin_amdgcn_readfirstlane(csr[rp + e]);
        int s1 = __builtin_amdgcn_readfirstlane(csr[rp + e + 1]);
        int s2 = __builtin_amdgcn_readfirstlane(csr[rp + e + 2]);
        int s3 = __builtin_amdgcn_readfirstlane(csr[rp + e + 3]);
        float v0 = h2s[(size_t)s0 * CLS + cl];
        float v1 = h2s[(size_t)s1 * CLS + cl];
        float v2 = h2s[(size_t)s2 * CLS + cl];
        float v3 = h2s[(size_t)s3 * CLS + cl];
        acc += (v0 + v1) + (v2 + v3);
    }
    for (; e < cnt; e++) {
        int s = __builtin_amdgcn_readfirstlane(csr[rp + e]);
        acc += h2s[(size_t)s * CLS + cl];
    }
    if (lane < CLS)
        out[(size_t)n * CLS + lane] = acc * dinv[n] + b2[lane];
}

// ===========================================================================
// Launch
// ===========================================================================
extern "C" void kernel_launch(void* const* d_in, const int* in_sizes, int n_in,
                              void* d_out, int out_size, void* d_ws, size_t ws_size,
                              hipStream_t stream) {
    const float* x   = (const float*)d_in[0];
    const float* W1  = (const float*)d_in[1];
    const float* b1  = (const float*)d_in[2];
    const float* W2  = (const float*)d_in[3];
    const float* b2  = (const float*)d_in[4];
    const int*   edg = (const int*)d_in[5];
    const int* src = edg;        // edges[0][:]
    const int* dst = edg + EE;   // edges[1][:]
    float* out = (float*)d_out;
    char* ws = (char*)d_ws;

    const int nb_n = NB_N;               // 391
    const int nb_e = (EE + 255) / 256;   // 6250

    // Workspace layout:
    //   deg   @ 0         (512 KB)   rowp @ 512K   dinv @ 1M   bsum @ 1.5M
    //   boff  @ 1.75M     csr  @ 2M  (6.4 MB)
    //   hs    @ 10M       (25.6 MB; reused as h2s [16 MB] after agg1)
    //   acc1  @ 36M       (25.6 MB; first 400 KB doubles as cursor pre-agg1)
    int*   deg    = (int*)(ws);
    int*   rowp   = (int*)(ws + (512 << 10));
    float* dinv   = (float*)(ws + (1 << 20));
    int*   bsum   = (int*)(ws + ((1 << 20) + (512 << 10)));
    int*   boff   = (int*)(ws + ((1 << 20) + (768 << 10)));
    int*   csr    = (int*)(ws + (2 << 20));
    float* hs     = (float*)(ws + (10 << 20));
    float* acc1   = (float*)(ws + (36 << 20));
    int*   cursor = (int*)acc1;     // dead before agg1 writes acc1
    float* h2s    = hs;             // hs dead after agg1

    k_zero<<<nb_n, 256, 0, stream>>>(deg);
    k_count<<<nb_e, 256, 0, stream>>>(dst, deg);
    k_scan_bsum<<<nb_n, 256, 0, stream>>>(deg, bsum);
    k_scan_boff<<<1, 512, 0, stream>>>(bsum, boff);
    k_scan_fin<<<nb_n, 256, 0, stream>>>(deg, boff, rowp, cursor, dinv);
    k_fill<<<nb_e, 256, 0, stream>>>(src, dst, cursor, csr);

    k_gemm1<<<3125, 256, 0, stream>>>(x, W1, dinv, hs);           // 12500 waves
    k_agg1<<<(NN + 3) / 4, 256, 0, stream>>>(rowp, deg, csr, dinv, b1, hs, acc1);
    k_gemm2<<<3125, 256, 0, stream>>>(acc1, W2, dinv, h2s);       // 12500 waves
    k_agg2<<<(NN + 3) / 4, 256, 0, stream>>>(rowp, deg, csr, dinv, b2, h2s, out);
}